// Round 14
// baseline (212.409 us; speedup 1.0000x reference)
//
#include <hip/hip_runtime.h>
#include <hip/hip_bf16.h>
#include <stdint.h>

// ---------- common ----------
typedef __attribute__((ext_vector_type(8))) short bf16x8;
typedef __attribute__((ext_vector_type(4))) float f32x4;

__device__ __forceinline__ ushort f2bf(float f) {
    union { float f; uint32_t u; } c; c.f = f;
    uint32_t u = c.u;
    uint32_t r = (u + 0x7FFFu + ((u >> 16) & 1u)) >> 16;
    return (ushort)r;
}

__device__ __forceinline__ void load16_to_lds(const void* gsrc, void* ldst) {
    __builtin_amdgcn_global_load_lds(
        (const __attribute__((address_space(1))) uint32_t*)gsrc,
        (__attribute__((address_space(3))) uint32_t*)ldst,
        16, 0, 0);
}

#define FENCE() asm volatile("" ::: "memory")
#define BARRIER() do { FENCE(); __builtin_amdgcn_s_barrier(); FENCE(); } while (0)
#define VMCNT(n) asm volatile("s_waitcnt vmcnt(" #n ")" ::: "memory")

// ---------- f32 -> bf16 convert ----------
__global__ __launch_bounds__(256) void f32_to_bf16_kernel(
    const float* __restrict__ in, ushort* __restrict__ out, int n)
{
    int i = (blockIdx.x * 256 + threadIdx.x) * 4;
    if (i >= n) return;
    float4 v = *(const float4*)(in + i);
    ushort4 o;
    o.x = f2bf(v.x); o.y = f2bf(v.y); o.z = f2bf(v.z); o.w = f2bf(v.w);
    *(ushort4*)(out + i) = o;
}

// ---------- feature transpose: [2,256,32,32] -> [2,32,32,256] ----------
__global__ __launch_bounds__(256) void transpose_feat_kernel(
    const float* __restrict__ feat, float* __restrict__ featT)
{
    int bc = blockIdx.x;
    int b = bc >> 8;
    int c = bc & 255;
    const float* src = feat + (size_t)bc * 1024;
    float* dst = featT + (size_t)b * 262144 + c;
    #pragma unroll
    for (int i = 0; i < 4; ++i) {
        int p = i * 256 + threadIdx.x;
        dst[(size_t)p * 256] = src[p];
    }
}

// ---------- ROI align v5: SEPARABLE ----------
__global__ __launch_bounds__(512) void roi_align_kernel(
    const float* __restrict__ featT, const float* __restrict__ props,
    ushort* __restrict__ pooled)
{
    int roi = blockIdx.x;
    int b = roi >> 10;
    __shared__ int   si0[28];
    __shared__ int   si1[28];
    __shared__ float sl[28];
    __shared__ float sv[28];
    __shared__ float Aw[7][10];
    __shared__ float Bw[7][10];
    __shared__ __align__(16) ushort outbuf[12544];
    int tid = threadIdx.x;
    if (tid < 28) {
        int axis = (tid >= 14) ? 1 : 0;
        int pp = tid - axis * 14;
        float c0 = props[roi * 4 + (axis ? 0 : 1)] * (1.f / 32.f);
        float c1 = props[roi * 4 + (axis ? 2 : 3)] * (1.f / 32.f);
        float sz = fmaxf(c1 - c0, 1.f);
        float bsz = sz * (1.f / 7.f);
        float g = (float)(pp >> 1) + ((float)(pp & 1) + 0.5f) * 0.5f;
        float c = c0 + g * bsz;
        float valid = (c > -1.f && c < 32.f) ? 1.f : 0.f;
        float cc = fminf(fmaxf(c, 0.f), 31.f);
        float fl = floorf(cc);
        int i0 = (int)fl;
        si0[tid] = i0;
        si1[tid] = min(i0 + 1, 31);
        sl[tid] = cc - fl;
        sv[tid] = valid;
    }
    __syncthreads();

    const int r0 = si0[0];
    const int c0 = si0[14];

    if (tid < 140) {
        int axis = tid / 70;
        int e = tid - axis * 70;
        int oy = e / 10, yy = e - oy * 10;
        int base = axis * 14;
        int org = axis ? c0 : r0;
        float wsum = 0.f;
        #pragma unroll
        for (int s = 0; s < 2; ++s) {
            int p = base + oy * 2 + s;
            float w = 0.f;
            if (si0[p] - org == yy) w += 1.f - sl[p];
            if (si1[p] - org == yy) w += sl[p];
            wsum += sv[p] * w;
        }
        wsum *= 0.5f;
        if (axis == 0) Aw[oy][yy] = wsum;
        else           Bw[oy][yy] = wsum;
    }
    __syncthreads();

    const int grp = tid >> 8;
    const int ch = tid & 255;
    const float* fbase = featT + (size_t)b * 262144 + ch;

    int xoff[10];
    #pragma unroll
    for (int x = 0; x < 10; ++x) xoff[x] = min(c0 + x, 31) * 256;

    if (grp == 0) {
        float t[4][10];
        #pragma unroll
        for (int oy = 0; oy < 4; ++oy)
            #pragma unroll
            for (int x = 0; x < 10; ++x) t[oy][x] = 0.f;
        #pragma unroll
        for (int y = 0; y < 10; ++y) {
            const float* frow = fbase + (size_t)min(r0 + y, 31) * 8192;
            float a0 = Aw[0][y], a1 = Aw[1][y], a2 = Aw[2][y], a3 = Aw[3][y];
            #pragma unroll
            for (int x = 0; x < 10; ++x) {
                float fv = frow[xoff[x]];
                t[0][x] += a0 * fv;
                t[1][x] += a1 * fv;
                t[2][x] += a2 * fv;
                t[3][x] += a3 * fv;
            }
        }
        #pragma unroll
        for (int oy = 0; oy < 4; ++oy)
            #pragma unroll
            for (int ox = 0; ox < 7; ++ox) {
                float o = 0.f;
                #pragma unroll
                for (int x = 0; x < 10; ++x) o += Bw[ox][x] * t[oy][x];
                outbuf[ch * 49 + oy * 7 + ox] = f2bf(o);
            }
    } else {
        float t[3][10];
        #pragma unroll
        for (int oy = 0; oy < 3; ++oy)
            #pragma unroll
            for (int x = 0; x < 10; ++x) t[oy][x] = 0.f;
        #pragma unroll
        for (int y = 0; y < 10; ++y) {
            const float* frow = fbase + (size_t)min(r0 + y, 31) * 8192;
            float a4 = Aw[4][y], a5 = Aw[5][y], a6 = Aw[6][y];
            #pragma unroll
            for (int x = 0; x < 10; ++x) {
                float fv = frow[xoff[x]];
                t[0][x] += a4 * fv;
                t[1][x] += a5 * fv;
                t[2][x] += a6 * fv;
            }
        }
        #pragma unroll
        for (int oy = 0; oy < 3; ++oy)
            #pragma unroll
            for (int ox = 0; ox < 7; ++ox) {
                float o = 0.f;
                #pragma unroll
                for (int x = 0; x < 10; ++x) o += Bw[ox][x] * t[oy][x];
                outbuf[ch * 49 + (4 + oy) * 7 + ox] = f2bf(o);
            }
    }
    __syncthreads();

    const uint4* src = (const uint4*)outbuf;
    uint4* dst = (uint4*)(pooled + (size_t)roi * 12544);
    #pragma unroll
    for (int i = 0; i < 4; ++i) {
        int idx = i * 512 + tid;
        if (idx < 1568) dst[idx] = src[idx];
    }
}

// ---------- 8-phase 256x256 split-K GEMM, pipelined operand reads ----------
// R13 fix vs R12: each quadrant's ds_reads issue DURING the previous quadrant's
// MFMA section (reads after publish barrier, consumer one phase later), so LDS
// latency hides under MFMA instead of serializing.  Stage/vmcnt order identical
// to the R12-verified schedule.  Barriers: publish@P0,P1 (vmcnt(8) each),
// close@P1,P2,P3 (order region overwrites vs last readers).
#define STAGE_A8(BB, HALF, KOFF) do { \
    _Pragma("unroll") for (int r_ = 0; r_ < 2; ++r_) { \
        int rbase_ = (HALF) * 128 + r_ * 64 + w * 8; \
        int row_ = rbase_ + (l >> 3); \
        int c16s_ = (l & 7) ^ (row_ & 7); \
        load16_to_lds((const char*)(Ap + (size_t)(m0 + row_) * K + (KOFF)) + c16s_ * 16, \
                      &sA[BB][rbase_][0]); \
    } } while (0)
#define STAGE_B8(BB, Q, KOFF) do { \
    _Pragma("unroll") for (int r_ = 0; r_ < 2; ++r_) { \
        int rl_ = r_ * 64 + w * 8 + (l >> 3); \
        int brow_ = ((rl_ >> 5) << 6) + (Q) * 32 + (rl_ & 31); \
        int c16s_ = (l & 7) ^ (rl_ & 7); \
        load16_to_lds((const char*)(Bp + (size_t)(n0 + brow_) * K + (KOFF)) + c16s_ * 16, \
                      &sB[BB][(Q) * 128 + r_ * 64 + w * 8][0]); \
    } } while (0)
#define LOADREGS(RA, RB, QM, QN) do { \
    _Pragma("unroll") for (int mm_ = 0; mm_ < 4; ++mm_) \
        _Pragma("unroll") for (int kk_ = 0; kk_ < 2; ++kk_) { \
            int lr_ = wm * 128 + (QM) * 64 + mm_ * 16 + lrow; \
            int c16_ = (kk_ * 4 + khi) ^ (lrow & 7); \
            RA[mm_ * 2 + kk_] = *(const bf16x8*)&sA[cur][lr_][c16_ * 8]; \
        } \
    _Pragma("unroll") for (int nn_ = 0; nn_ < 2; ++nn_) \
        _Pragma("unroll") for (int kk_ = 0; kk_ < 2; ++kk_) { \
            int lrB_ = (QN) * 128 + wn * 32 + nn_ * 16 + lrow; \
            int c16_ = (kk_ * 4 + khi) ^ (lrow & 7); \
            RB[nn_ * 2 + kk_] = *(const bf16x8*)&sB[cur][lrB_][c16_ * 8]; \
        } \
} while (0)
#define MFMAQ(RA, RB, QM, QN) do { \
    __builtin_amdgcn_s_setprio(1); \
    _Pragma("unroll") for (int mm_ = 0; mm_ < 4; ++mm_) \
        _Pragma("unroll") for (int nn_ = 0; nn_ < 2; ++nn_) \
            _Pragma("unroll") for (int kk_ = 0; kk_ < 2; ++kk_) \
                acc[(QM) * 4 + mm_][(QN) * 2 + nn_] = __builtin_amdgcn_mfma_f32_16x16x32_bf16( \
                    RA[mm_ * 2 + kk_], RB[nn_ * 2 + kk_], acc[(QM) * 4 + mm_][(QN) * 2 + nn_], 0, 0, 0); \
    __builtin_amdgcn_s_setprio(0); \
} while (0)

__global__ __launch_bounds__(512) void gemm_8ph(
    const ushort* __restrict__ Ap, const ushort* __restrict__ Bp,
    float* __restrict__ part, int M, int N, int K, int klen)
{
    __shared__ __align__(16) ushort sA[2][256][64];   // 64 KB
    __shared__ __align__(16) ushort sB[2][256][64];   // 64 KB
    const int tid = threadIdx.x;

    const int nbx = gridDim.x, nby = gridDim.y;
    const int nwg = nbx * nby * gridDim.z;
    const int d = blockIdx.x + nbx * (blockIdx.y + nby * blockIdx.z);
    const int t = (d & 7) * (nwg >> 3) + (d >> 3);
    const int n_blk = t % nbx;
    const int m_blk = (t / nbx) % nby;
    const int k_blk = t / (nbx * nby);

    const int m0 = m_blk * 256;
    const int n0 = n_blk * 256;
    const int k_start = k_blk * klen;
    const int nt = klen >> 6;

    const int w = tid >> 6, l = tid & 63;
    const int wm = w >> 2, wn = w & 3;
    const int lrow = l & 15, khi = l >> 4;

    f32x4 acc[8][4] = {};

    // prologue: steady-state issue order as if tiles -2,-1 had run
    {
        int k0 = k_start, k1 = k_start + 64;
        STAGE_B8(0, 0, k0);   // B0'(0)
        STAGE_A8(0, 1, k0);   // A1(0)
        STAGE_A8(0, 0, k0);   // A0(0)
        STAGE_B8(0, 1, k0);   // B1'(0)
        STAGE_B8(1, 0, k1);   // B0'(1)
        STAGE_A8(1, 1, k1);   // A1(1)
    }

    int cur = 0;
    for (int T = 0; T < nt - 1; ++T) {
        const int koff1 = k_start + (T + 1) * 64;
        const int koff2 = k_start + (T + 2) * 64;
        const int nxt = cur ^ 1;
        const bool has2 = (T + 2) < nt;
        bf16x8 r0a[8], r0b[4], r1a[8], r1b[4], r2a[8], r2b[4], r3a[8], r3b[4];

        // P0: publish A0(T) (+older); reads for q0 AND q1 overlap MFMA(q0)
        STAGE_A8(nxt, 0, koff1);
        VMCNT(8);
        BARRIER();
        LOADREGS(r0a, r0b, 0, 0);
        LOADREGS(r1a, r1b, 1, 0);
        MFMAQ(r0a, r0b, 0, 0);

        // P1: publish B1'(T); reads for q2 overlap MFMA(q1)
        STAGE_B8(nxt, 1, koff1);
        VMCNT(8);
        BARRIER();
        LOADREGS(r2a, r2b, 1, 1);
        MFMAQ(r1a, r1b, 1, 0);
        BARRIER();                 // close1: B0'(cur) reads (r0/r1) complete

        // P2: stage B0'(T+2) into cur (region dead); reads q3 overlap MFMA(q2)
        if (has2) STAGE_B8(cur, 0, koff2);
        LOADREGS(r3a, r3b, 0, 1);
        MFMAQ(r2a, r2b, 1, 1);
        BARRIER();                 // close2: A1(cur) reads (r1/r2) complete

        // P3: stage A1(T+2) into cur (region dead)
        if (has2) STAGE_A8(cur, 1, koff2);
        MFMAQ(r3a, r3b, 0, 1);
        BARRIER();                 // close3: A0/B1'(cur) reads (r3) complete
        cur ^= 1;
    }
    // last tile: everything staged; single drain, no further barriers
    VMCNT(0);
    BARRIER();
    {
        bf16x8 ra[8], rb[4];
        LOADREGS(ra, rb, 0, 0); MFMAQ(ra, rb, 0, 0);
        LOADREGS(ra, rb, 1, 0); MFMAQ(ra, rb, 1, 0);
        LOADREGS(ra, rb, 1, 1); MFMAQ(ra, rb, 1, 1);
        LOADREGS(ra, rb, 0, 1); MFMAQ(ra, rb, 0, 1);
    }

    // epilogue: raw f32 partials
    const int r4 = (l >> 4) * 4;
    const int cc = l & 15;
    float* pb = part + (size_t)k_blk * M * N;
    #pragma unroll
    for (int m = 0; m < 8; ++m) {
        #pragma unroll
        for (int n = 0; n < 4; ++n) {
            int col = n0 + wn * 64 + n * 16 + cc;
            #pragma unroll
            for (int j = 0; j < 4; ++j) {
                int row = m0 + wm * 128 + m * 16 + r4 + j;
                pb[(size_t)row * N + col] = acc[m][n][j];
            }
        }
    }
}

// ---------- split-K bf16 MFMA GEMM, double-buffered 2-phase (gemm2 + fallback) ----------
__global__ __launch_bounds__(256) void gemm_bt_split(
    const ushort* __restrict__ A, const ushort* __restrict__ Bm,
    float* __restrict__ part, int M, int N, int K, int klen)
{
    constexpr int BK = 32;
    __shared__ __align__(16) ushort lA[2][128][BK];
    __shared__ __align__(16) ushort lB[2][128][BK];
    const int tid = threadIdx.x;

    const int nbx = gridDim.x, nby = gridDim.y;
    const int nwg = nbx * nby * gridDim.z;
    const int d = blockIdx.x + nbx * (blockIdx.y + nby * blockIdx.z);
    const int t = (d & 7) * (nwg >> 3) + (d >> 3);
    const int n_blk = t % nbx;
    const int m_blk = (t / nbx) % nby;
    const int k_blk = t / (nbx * nby);

    const int m0 = m_blk * 128;
    const int n0 = n_blk * 128;
    const int k_start = k_blk * klen;

    const int w = tid >> 6, l = tid & 63;
    const int wr = w >> 1, wcid = w & 1;
    const int lrow = l & 15;
    const int lkb = (((l >> 4) ^ ((lrow >> 1) & 3)) * 16);

    const int sc0 = tid, sc1 = 256 + tid;
    const int srow0 = sc0 >> 2, srow1 = sc1 >> 2;
    const int scol0 = ((sc0 & 3) ^ ((srow0 >> 1) & 3)) * 16;
    const int scol1 = ((sc1 & 3) ^ ((srow1 >> 1) & 3)) * 16;

    const int nsteps = klen / BK;

    {
        int k0 = k_start;
        load16_to_lds((const char*)(A + (size_t)(m0 + srow0) * K + k0) + scol0, ((char*)lA[0]) + sc0 * 16);
        load16_to_lds((const char*)(A + (size_t)(m0 + srow1) * K + k0) + scol1, ((char*)lA[0]) + sc1 * 16);
        load16_to_lds((const char*)(Bm + (size_t)(n0 + srow0) * K + k0) + scol0, ((char*)lB[0]) + sc0 * 16);
        load16_to_lds((const char*)(Bm + (size_t)(n0 + srow1) * K + k0) + scol1, ((char*)lB[0]) + sc1 * 16);
    }
    __syncthreads();

    f32x4 acc[4][4] = {};
    int cur = 0;

    for (int ts = 0; ts < nsteps; ++ts) {
        if (ts + 1 < nsteps) {
            int k0 = k_start + (ts + 1) * BK;
            int nxt = cur ^ 1;
            load16_to_lds((const char*)(A + (size_t)(m0 + srow0) * K + k0) + scol0, ((char*)lA[nxt]) + sc0 * 16);
            load16_to_lds((const char*)(A + (size_t)(m0 + srow1) * K + k0) + scol1, ((char*)lA[nxt]) + sc1 * 16);
            load16_to_lds((const char*)(Bm + (size_t)(n0 + srow0) * K + k0) + scol0, ((char*)lB[nxt]) + sc0 * 16);
            load16_to_lds((const char*)(Bm + (size_t)(n0 + srow1) * K + k0) + scol1, ((char*)lB[nxt]) + sc1 * 16);
        }

        bf16x8 af[4], bfr[4];
        #pragma unroll
        for (int m = 0; m < 4; ++m)
            af[m] = *(const bf16x8*)(((const char*)lA[cur]) + (wr * 64 + m * 16 + lrow) * 64 + lkb);
        #pragma unroll
        for (int n = 0; n < 4; ++n)
            bfr[n] = *(const bf16x8*)(((const char*)lB[cur]) + (wcid * 64 + n * 16 + lrow) * 64 + lkb);
        #pragma unroll
        for (int m = 0; m < 4; ++m)
            #pragma unroll
            for (int n = 0; n < 4; ++n)
                acc[m][n] = __builtin_amdgcn_mfma_f32_16x16x32_bf16(af[m], bfr[n], acc[m][n], 0, 0, 0);

        __syncthreads();
        cur ^= 1;
    }

    const int r4 = (l >> 4) * 4;
    const int cc = l & 15;
    float* pb = part + (size_t)k_blk * M * N;
    #pragma unroll
    for (int m = 0; m < 4; ++m) {
        #pragma unroll
        for (int n = 0; n < 4; ++n) {
            int col = n0 + wcid * 64 + n * 16 + cc;
            #pragma unroll
            for (int j = 0; j < 4; ++j) {
                int row = m0 + wr * 64 + m * 16 + r4 + j;
                pb[(size_t)row * N + col] = acc[m][n][j];
            }
        }
    }
}

// ---------- reduce split-K partials + bias + relu + optional bf16 cast ----------
template<bool OUT_BF16>
__global__ __launch_bounds__(256) void reduce_split_kernel(
    const float* __restrict__ part, const float* __restrict__ bias,
    void* __restrict__ out, int MN, int N, int S, int relu)
{
    int i4 = (blockIdx.x * 256 + threadIdx.x) * 4;
    if (i4 >= MN) return;
    float4 a = *(const float4*)(part + i4);
    for (int s = 1; s < S; ++s) {
        float4 b = *(const float4*)(part + (size_t)s * MN + i4);
        a.x += b.x; a.y += b.y; a.z += b.z; a.w += b.w;
    }
    int bc = i4 & (N - 1);
    float4 bv = *(const float4*)(bias + bc);
    a.x += bv.x; a.y += bv.y; a.z += bv.z; a.w += bv.w;
    if (relu) {
        a.x = fmaxf(a.x, 0.f); a.y = fmaxf(a.y, 0.f);
        a.z = fmaxf(a.z, 0.f); a.w = fmaxf(a.w, 0.f);
    }
    if (OUT_BF16) {
        ushort4 o; o.x = f2bf(a.x); o.y = f2bf(a.y); o.z = f2bf(a.z); o.w = f2bf(a.w);
        *(ushort4*)((ushort*)out + i4) = o;
    } else {
        *(float4*)((float*)out + i4) = a;
    }
}

// ---------- fallback fused GEMM ----------
template<bool OUT_BF16>
__global__ __launch_bounds__(256) void gemm_bt(
    const ushort* __restrict__ A, const ushort* __restrict__ Bm,
    const float* __restrict__ bias, void* __restrict__ Cout,
    int M, int N, int K, int relu)
{
    constexpr int BM = 128, BN = 64, BK = 32;
    __shared__ __align__(16) ushort lA[BM][BK];
    __shared__ __align__(16) ushort lB[BN][BK];
    const int tid = threadIdx.x;
    const int m0 = blockIdx.y * BM;
    const int n0 = blockIdx.x * BN;
    const int w = tid >> 6, l = tid & 63;
    const int wr = w >> 1, wcid = w & 1;
    const int lrow = l & 15, lk = (l >> 4) * 8;

    f32x4 acc[4][2] = {};

    for (int k0 = 0; k0 < K; k0 += BK) {
        __syncthreads();
        #pragma unroll
        for (int i = 0; i < 2; ++i) {
            int chunk = i * 256 + tid;
            int row = chunk >> 2;
            int colb = (chunk & 3) * 16;
            load16_to_lds((const char*)(A + (size_t)(m0 + row) * K + k0) + colb, ((char*)lA) + chunk * 16);
        }
        {
            int chunk = tid;
            int row = chunk >> 2;
            int colb = (chunk & 3) * 16;
            load16_to_lds((const char*)(Bm + (size_t)(n0 + row) * K + k0) + colb, ((char*)lB) + chunk * 16);
        }
        __syncthreads();

        bf16x8 af[4], bfr[2];
        #pragma unroll
        for (int m = 0; m < 4; ++m)
            af[m] = *(const bf16x8*)&lA[wr * 64 + m * 16 + lrow][lk];
        #pragma unroll
        for (int n = 0; n < 2; ++n)
            bfr[n] = *(const bf16x8*)&lB[wcid * 32 + n * 16 + lrow][lk];
        #pragma unroll
        for (int m = 0; m < 4; ++m)
            #pragma unroll
            for (int n = 0; n < 2; ++n)
                acc[m][n] = __builtin_amdgcn_mfma_f32_16x16x32_bf16(af[m], bfr[n], acc[m][n], 0, 0, 0);
    }

    const int r4 = (l >> 4) * 4;
    const int cc = l & 15;
    #pragma unroll
    for (int m = 0; m < 4; ++m) {
        #pragma unroll
        for (int n = 0; n < 2; ++n) {
            int col = n0 + wcid * 32 + n * 16 + cc;
            float bv = bias[col];
            #pragma unroll
            for (int j = 0; j < 4; ++j) {
                int row = m0 + wr * 64 + m * 16 + r4 + j;
                float v = acc[m][n][j] + bv;
                if (relu) v = fmaxf(v, 0.f);
                if (OUT_BF16) ((ushort*)Cout)[(size_t)row * N + col] = f2bf(v);
                else          ((float*)Cout)[(size_t)row * N + col] = v;
            }
        }
    }
}

// ---------- heads ----------
__global__ __launch_bounds__(256) void heads_kernel(
    const float* __restrict__ x2,
    const float* __restrict__ wc, const float* __restrict__ bc,
    const float* __restrict__ wb, const float* __restrict__ bb,
    float* __restrict__ out)
{
    int w = threadIdx.x >> 6, l = threadIdx.x & 63;
    int row = blockIdx.x * 4 + w;
    const float* xr = x2 + (size_t)row * 1024;
    float acc[10];
    #pragma unroll
    for (int o = 0; o < 10; ++o) acc[o] = 0.f;
    for (int i = 0; i < 16; ++i) {
        int k = i * 64 + l;
        float xv = xr[k];
        #pragma unroll
        for (int o = 0; o < 2; ++o) acc[o] += xv * wc[o * 1024 + k];
        #pragma unroll
        for (int o = 0; o < 8; ++o) acc[2 + o] += xv * wb[o * 1024 + k];
    }
    #pragma unroll
    for (int o = 0; o < 10; ++o) {
        float v = acc[o];
        #pragma unroll
        for (int s = 32; s > 0; s >>= 1) v += __shfl_xor(v, s, 64);
        acc[o] = v;
    }
    if (l == 0) {
        float* cls = out;
        float* bbx = out + 2048 * 2;
        cls[row * 2 + 0] = acc[0] + bc[0];
        cls[row * 2 + 1] = acc[1] + bc[1];
        #pragma unroll
        for (int o = 0; o < 8; ++o) bbx[row * 8 + o] = acc[2 + o] + bb[o];
    }
}

// ---------- decode + softmax ----------
__global__ __launch_bounds__(256) void decode_kernel(
    const float* __restrict__ props, float* __restrict__ out)
{
    int r = blockIdx.x * 256 + threadIdx.x;
    if (r >= 2048) return;
    const float* cls = out;
    const float* bbx = out + 4096;
    float* boxes  = out + 20480;
    float* scores = out + 36864;
    float px1 = props[r * 4 + 0], py1 = props[r * 4 + 1];
    float px2 = props[r * 4 + 2], py2 = props[r * 4 + 3];
    float pw = px2 - px1, ph = py2 - py1;
    float cx = px1 + 0.5f * pw, cy = py1 + 0.5f * ph;
    const float CLIP = 4.135166556742356f;
    #pragma unroll
    for (int k = 0; k < 2; ++k) {
        float dx = bbx[r * 8 + k * 4 + 0] * 0.1f;
        float dy = bbx[r * 8 + k * 4 + 1] * 0.1f;
        float dw = fminf(bbx[r * 8 + k * 4 + 2] * 0.2f, CLIP);
        float dh = fminf(bbx[r * 8 + k * 4 + 3] * 0.2f, CLIP);
        float pcx = dx * pw + cx, pcy = dy * ph + cy;
        float ppw = expf(dw) * pw, pph = expf(dh) * ph;
        float v0 = pcx - 0.5f * ppw, v1 = pcy - 0.5f * pph;
        float v2 = pcx + 0.5f * ppw, v3 = pcy + 0.5f * pph;
        boxes[r * 8 + k * 4 + 0] = fminf(fmaxf(v0, 0.f), 1024.f);
        boxes[r * 8 + k * 4 + 1] = fminf(fmaxf(v1, 0.f), 1024.f);
        boxes[r * 8 + k * 4 + 2] = fminf(fmaxf(v2, 0.f), 1024.f);
        boxes[r * 8 + k * 4 + 3] = fminf(fmaxf(v3, 0.f), 1024.f);
    }
    float s0 = cls[r * 2], s1 = cls[r * 2 + 1];
    float m = fmaxf(s0, s1);
    float e0 = expf(s0 - m), e1 = expf(s1 - m);
    float inv = 1.f / (e0 + e1);
    scores[r * 2 + 0] = e0 * inv;
    scores[r * 2 + 1] = e1 * inv;
}

// ---------- launch ----------
extern "C" void kernel_launch(void* const* d_in, const int* in_sizes, int n_in,
                              void* d_out, int out_size, void* d_ws, size_t ws_size,
                              hipStream_t stream) {
    const float* feat  = (const float*)d_in[0];
    const float* props = (const float*)d_in[1];
    const float* w1    = (const float*)d_in[2];
    const float* b1    = (const float*)d_in[3];
    const float* w2    = (const float*)d_in[4];
    const float* b2    = (const float*)d_in[5];
    const float* wc    = (const float*)d_in[6];
    const float* bc    = (const float*)d_in[7];
    const float* wb    = (const float*)d_in[8];
    const float* bb    = (const float*)d_in[9];
    float* out = (float*)d_out;

    char* ws = (char*)d_ws;
    ushort* pooled = (ushort*)(ws);                          // 51,380,224 B
    ushort* w1b    = (ushort*)(ws + 51380224);               // 25,690,112 B
    ushort* w2b    = (ushort*)(ws + 51380224 + 25690112);    //  2,097,152 B
    ushort* x1     = (ushort*)(ws + 79167488);               //  4,194,304 B
    float*  x2     = (float*) (ws + 83361792);               //  8,388,608 B
    float*  featT  = (float*) (ws + 83361792);               // aliases x2 (dead by gemm2)
    float*  part   = (float*) (ws + 91750400);               // split-K partials
    const size_t WS_NEED7 = 91750400 + (size_t)7 * 8388608;  // 8ph splitK=7
    const size_t WS_NEED4 = 91750400 + 33554432;

    const int M = 2048, N = 1024;
    const int MN = M * N;

    f32_to_bf16_kernel<<<12845056 / 1024, 256, 0, stream>>>(w1, w1b, 12845056);
    f32_to_bf16_kernel<<<1048576 / 1024, 256, 0, stream>>>(w2, w2b, 1048576);
    transpose_feat_kernel<<<512, 256, 0, stream>>>(feat, featT);
    roi_align_kernel<<<2048, 512, 0, stream>>>(featT, props, pooled);

    if (ws_size >= WS_NEED7) {
        gemm_8ph<<<dim3(N / 256, M / 256, 7), 512, 0, stream>>>(pooled, w1b, part, M, N, 12544, 1792);
        reduce_split_kernel<true ><<<MN / 1024, 256, 0, stream>>>(part, b1, x1, MN, N, 7, 1);
        gemm_bt_split<<<dim3(N / 128, M / 128, 4), 256, 0, stream>>>(x1, w2b, part, M, N, 1024, 256);
        reduce_split_kernel<false><<<MN / 1024, 256, 0, stream>>>(part, b2, x2, MN, N, 4, 1);
    } else if (ws_size >= WS_NEED4) {
        gemm_bt_split<<<dim3(N / 128, M / 128, 4), 256, 0, stream>>>(pooled, w1b, part, M, N, 12544, 3136);
        reduce_split_kernel<true ><<<MN / 1024, 256, 0, stream>>>(part, b1, x1, MN, N, 4, 1);
        gemm_bt_split<<<dim3(N / 128, M / 128, 4), 256, 0, stream>>>(x1, w2b, part, M, N, 1024, 256);
        reduce_split_kernel<false><<<MN / 1024, 256, 0, stream>>>(part, b2, x2, MN, N, 4, 1);
    } else {
        gemm_bt<true ><<<dim3(N / 64, M / 128), 256, 0, stream>>>(pooled, w1b, b1, x1, M, N, 12544, 1);
        gemm_bt<false><<<dim3(N / 64, M / 128), 256, 0, stream>>>(x1, w2b, b2, x2, M, N, 1024, 1);
    }

    heads_kernel<<<512, 256, 0, stream>>>(x2, wc, bc, wb, bb, out);
    decode_kernel<<<8, 256, 0, stream>>>(props, out);
}

// Round 15
// 196.499 us; speedup vs baseline: 1.0810x; 1.0810x over previous
//
#include <hip/hip_runtime.h>
#include <hip/hip_bf16.h>
#include <stdint.h>

// ---------- common ----------
typedef __attribute__((ext_vector_type(8))) short bf16x8;
typedef __attribute__((ext_vector_type(4))) float f32x4;

__device__ __forceinline__ ushort f2bf(float f) {
    union { float f; uint32_t u; } c; c.f = f;
    uint32_t u = c.u;
    uint32_t r = (u + 0x7FFFu + ((u >> 16) & 1u)) >> 16;
    return (ushort)r;
}

__device__ __forceinline__ void load16_to_lds(const void* gsrc, void* ldst) {
    __builtin_amdgcn_global_load_lds(
        (const __attribute__((address_space(1))) uint32_t*)gsrc,
        (__attribute__((address_space(3))) uint32_t*)ldst,
        16, 0, 0);
}

// ---------- f32 -> bf16 convert ----------
__global__ __launch_bounds__(256) void f32_to_bf16_kernel(
    const float* __restrict__ in, ushort* __restrict__ out, int n)
{
    int i = (blockIdx.x * 256 + threadIdx.x) * 4;
    if (i >= n) return;
    float4 v = *(const float4*)(in + i);
    ushort4 o;
    o.x = f2bf(v.x); o.y = f2bf(v.y); o.z = f2bf(v.z); o.w = f2bf(v.w);
    *(ushort4*)(out + i) = o;
}

// ---------- feature transpose: [2,256,32,32] -> [2,32,32,256] ----------
__global__ __launch_bounds__(256) void transpose_feat_kernel(
    const float* __restrict__ feat, float* __restrict__ featT)
{
    int bc = blockIdx.x;
    int b = bc >> 8;
    int c = bc & 255;
    const float* src = feat + (size_t)bc * 1024;
    float* dst = featT + (size_t)b * 262144 + c;
    #pragma unroll
    for (int i = 0; i < 4; ++i) {
        int p = i * 256 + threadIdx.x;
        dst[(size_t)p * 256] = src[p];
    }
}

// ---------- ROI align v5: SEPARABLE ----------
__global__ __launch_bounds__(512) void roi_align_kernel(
    const float* __restrict__ featT, const float* __restrict__ props,
    ushort* __restrict__ pooled)
{
    int roi = blockIdx.x;
    int b = roi >> 10;
    __shared__ int   si0[28];
    __shared__ int   si1[28];
    __shared__ float sl[28];
    __shared__ float sv[28];
    __shared__ float Aw[7][10];
    __shared__ float Bw[7][10];
    __shared__ __align__(16) ushort outbuf[12544];
    int tid = threadIdx.x;
    if (tid < 28) {
        int axis = (tid >= 14) ? 1 : 0;
        int pp = tid - axis * 14;
        float c0 = props[roi * 4 + (axis ? 0 : 1)] * (1.f / 32.f);
        float c1 = props[roi * 4 + (axis ? 2 : 3)] * (1.f / 32.f);
        float sz = fmaxf(c1 - c0, 1.f);
        float bsz = sz * (1.f / 7.f);
        float g = (float)(pp >> 1) + ((float)(pp & 1) + 0.5f) * 0.5f;
        float c = c0 + g * bsz;
        float valid = (c > -1.f && c < 32.f) ? 1.f : 0.f;
        float cc = fminf(fmaxf(c, 0.f), 31.f);
        float fl = floorf(cc);
        int i0 = (int)fl;
        si0[tid] = i0;
        si1[tid] = min(i0 + 1, 31);
        sl[tid] = cc - fl;
        sv[tid] = valid;
    }
    __syncthreads();

    const int r0 = si0[0];
    const int c0 = si0[14];

    if (tid < 140) {
        int axis = tid / 70;
        int e = tid - axis * 70;
        int oy = e / 10, yy = e - oy * 10;
        int base = axis * 14;
        int org = axis ? c0 : r0;
        float wsum = 0.f;
        #pragma unroll
        for (int s = 0; s < 2; ++s) {
            int p = base + oy * 2 + s;
            float w = 0.f;
            if (si0[p] - org == yy) w += 1.f - sl[p];
            if (si1[p] - org == yy) w += sl[p];
            wsum += sv[p] * w;
        }
        wsum *= 0.5f;
        if (axis == 0) Aw[oy][yy] = wsum;
        else           Bw[oy][yy] = wsum;
    }
    __syncthreads();

    const int grp = tid >> 8;
    const int ch = tid & 255;
    const float* fbase = featT + (size_t)b * 262144 + ch;

    int xoff[10];
    #pragma unroll
    for (int x = 0; x < 10; ++x) xoff[x] = min(c0 + x, 31) * 256;

    if (grp == 0) {
        float t[4][10];
        #pragma unroll
        for (int oy = 0; oy < 4; ++oy)
            #pragma unroll
            for (int x = 0; x < 10; ++x) t[oy][x] = 0.f;
        #pragma unroll
        for (int y = 0; y < 10; ++y) {
            const float* frow = fbase + (size_t)min(r0 + y, 31) * 8192;
            float a0 = Aw[0][y], a1 = Aw[1][y], a2 = Aw[2][y], a3 = Aw[3][y];
            #pragma unroll
            for (int x = 0; x < 10; ++x) {
                float fv = frow[xoff[x]];
                t[0][x] += a0 * fv;
                t[1][x] += a1 * fv;
                t[2][x] += a2 * fv;
                t[3][x] += a3 * fv;
            }
        }
        #pragma unroll
        for (int oy = 0; oy < 4; ++oy)
            #pragma unroll
            for (int ox = 0; ox < 7; ++ox) {
                float o = 0.f;
                #pragma unroll
                for (int x = 0; x < 10; ++x) o += Bw[ox][x] * t[oy][x];
                outbuf[ch * 49 + oy * 7 + ox] = f2bf(o);
            }
    } else {
        float t[3][10];
        #pragma unroll
        for (int oy = 0; oy < 3; ++oy)
            #pragma unroll
            for (int x = 0; x < 10; ++x) t[oy][x] = 0.f;
        #pragma unroll
        for (int y = 0; y < 10; ++y) {
            const float* frow = fbase + (size_t)min(r0 + y, 31) * 8192;
            float a4 = Aw[4][y], a5 = Aw[5][y], a6 = Aw[6][y];
            #pragma unroll
            for (int x = 0; x < 10; ++x) {
                float fv = frow[xoff[x]];
                t[0][x] += a4 * fv;
                t[1][x] += a5 * fv;
                t[2][x] += a6 * fv;
            }
        }
        #pragma unroll
        for (int oy = 0; oy < 3; ++oy)
            #pragma unroll
            for (int ox = 0; ox < 7; ++ox) {
                float o = 0.f;
                #pragma unroll
                for (int x = 0; x < 10; ++x) o += Bw[ox][x] * t[oy][x];
                outbuf[ch * 49 + (4 + oy) * 7 + ox] = f2bf(o);
            }
    }
    __syncthreads();

    const uint4* src = (const uint4*)outbuf;
    uint4* dst = (uint4*)(pooled + (size_t)roi * 12544);
    #pragma unroll
    for (int i = 0; i < 4; ++i) {
        int idx = i * 512 + tid;
        if (idx < 1568) dst[idx] = src[idx];
    }
}

// ---------- split-K bf16 MFMA GEMM, double-buffered 2-phase (R12-proven) ----------
// part[kb][M][N] = A[M,Kchunk] @ B[N,Kchunk]^T.  BM=BN=128, BK=32, 4 waves.
// stage(buf^1, t+1) issued BEFORE compute(buf, t); single __syncthreads per
// step (implicit vmcnt(0) drain) -> race-free disjoint buffers.
__global__ __launch_bounds__(256) void gemm_bt_split(
    const ushort* __restrict__ A, const ushort* __restrict__ Bm,
    float* __restrict__ part, int M, int N, int K, int klen)
{
    constexpr int BK = 32;
    __shared__ __align__(16) ushort lA[2][128][BK];
    __shared__ __align__(16) ushort lB[2][128][BK];
    const int tid = threadIdx.x;

    // bijective XCD-chunked swizzle (nwg % 8 == 0 in all tiers)
    const int nbx = gridDim.x, nby = gridDim.y;
    const int nwg = nbx * nby * gridDim.z;
    const int d = blockIdx.x + nbx * (blockIdx.y + nby * blockIdx.z);
    const int t = (d & 7) * (nwg >> 3) + (d >> 3);
    const int n_blk = t % nbx;
    const int m_blk = (t / nbx) % nby;
    const int k_blk = t / (nbx * nby);

    const int m0 = m_blk * 128;
    const int n0 = n_blk * 128;
    const int k_start = k_blk * klen;

    const int w = tid >> 6, l = tid & 63;
    const int wr = w >> 1, wcid = w & 1;
    const int lrow = l & 15;
    const int lkb = (((l >> 4) ^ ((lrow >> 1) & 3)) * 16);

    const int sc0 = tid, sc1 = 256 + tid;
    const int srow0 = sc0 >> 2, srow1 = sc1 >> 2;
    const int scol0 = ((sc0 & 3) ^ ((srow0 >> 1) & 3)) * 16;
    const int scol1 = ((sc1 & 3) ^ ((srow1 >> 1) & 3)) * 16;

    const int nsteps = klen / BK;

    {
        int k0 = k_start;
        load16_to_lds((const char*)(A + (size_t)(m0 + srow0) * K + k0) + scol0, ((char*)lA[0]) + sc0 * 16);
        load16_to_lds((const char*)(A + (size_t)(m0 + srow1) * K + k0) + scol1, ((char*)lA[0]) + sc1 * 16);
        load16_to_lds((const char*)(Bm + (size_t)(n0 + srow0) * K + k0) + scol0, ((char*)lB[0]) + sc0 * 16);
        load16_to_lds((const char*)(Bm + (size_t)(n0 + srow1) * K + k0) + scol1, ((char*)lB[0]) + sc1 * 16);
    }
    __syncthreads();

    f32x4 acc[4][4] = {};
    int cur = 0;

    for (int ts = 0; ts < nsteps; ++ts) {
        if (ts + 1 < nsteps) {
            int k0 = k_start + (ts + 1) * BK;
            int nxt = cur ^ 1;
            load16_to_lds((const char*)(A + (size_t)(m0 + srow0) * K + k0) + scol0, ((char*)lA[nxt]) + sc0 * 16);
            load16_to_lds((const char*)(A + (size_t)(m0 + srow1) * K + k0) + scol1, ((char*)lA[nxt]) + sc1 * 16);
            load16_to_lds((const char*)(Bm + (size_t)(n0 + srow0) * K + k0) + scol0, ((char*)lB[nxt]) + sc0 * 16);
            load16_to_lds((const char*)(Bm + (size_t)(n0 + srow1) * K + k0) + scol1, ((char*)lB[nxt]) + sc1 * 16);
        }

        bf16x8 af[4], bfr[4];
        #pragma unroll
        for (int m = 0; m < 4; ++m)
            af[m] = *(const bf16x8*)(((const char*)lA[cur]) + (wr * 64 + m * 16 + lrow) * 64 + lkb);
        #pragma unroll
        for (int n = 0; n < 4; ++n)
            bfr[n] = *(const bf16x8*)(((const char*)lB[cur]) + (wcid * 64 + n * 16 + lrow) * 64 + lkb);
        #pragma unroll
        for (int m = 0; m < 4; ++m)
            #pragma unroll
            for (int n = 0; n < 4; ++n)
                acc[m][n] = __builtin_amdgcn_mfma_f32_16x16x32_bf16(af[m], bfr[n], acc[m][n], 0, 0, 0);

        __syncthreads();
        cur ^= 1;
    }

    const int r4 = (l >> 4) * 4;
    const int cc = l & 15;
    float* pb = part + (size_t)k_blk * M * N;
    #pragma unroll
    for (int m = 0; m < 4; ++m) {
        #pragma unroll
        for (int n = 0; n < 4; ++n) {
            int col = n0 + wcid * 64 + n * 16 + cc;
            #pragma unroll
            for (int j = 0; j < 4; ++j) {
                int row = m0 + wr * 64 + m * 16 + r4 + j;
                pb[(size_t)row * N + col] = acc[m][n][j];
            }
        }
    }
}

// ---------- reduce split-K partials + bias + relu + optional bf16 cast ----------
template<bool OUT_BF16>
__global__ __launch_bounds__(256) void reduce_split_kernel(
    const float* __restrict__ part, const float* __restrict__ bias,
    void* __restrict__ out, int MN, int N, int S, int relu)
{
    int i4 = (blockIdx.x * 256 + threadIdx.x) * 4;
    if (i4 >= MN) return;
    float4 a = *(const float4*)(part + i4);
    for (int s = 1; s < S; ++s) {
        float4 b = *(const float4*)(part + (size_t)s * MN + i4);
        a.x += b.x; a.y += b.y; a.z += b.z; a.w += b.w;
    }
    int bc = i4 & (N - 1);
    float4 bv = *(const float4*)(bias + bc);
    a.x += bv.x; a.y += bv.y; a.z += bv.z; a.w += bv.w;
    if (relu) {
        a.x = fmaxf(a.x, 0.f); a.y = fmaxf(a.y, 0.f);
        a.z = fmaxf(a.z, 0.f); a.w = fmaxf(a.w, 0.f);
    }
    if (OUT_BF16) {
        ushort4 o; o.x = f2bf(a.x); o.y = f2bf(a.y); o.z = f2bf(a.z); o.w = f2bf(a.w);
        *(ushort4*)((ushort*)out + i4) = o;
    } else {
        *(float4*)((float*)out + i4) = a;
    }
}

// ---------- fallback fused GEMM ----------
template<bool OUT_BF16>
__global__ __launch_bounds__(256) void gemm_bt(
    const ushort* __restrict__ A, const ushort* __restrict__ Bm,
    const float* __restrict__ bias, void* __restrict__ Cout,
    int M, int N, int K, int relu)
{
    constexpr int BM = 128, BN = 64, BK = 32;
    __shared__ __align__(16) ushort lA[BM][BK];
    __shared__ __align__(16) ushort lB[BN][BK];
    const int tid = threadIdx.x;
    const int m0 = blockIdx.y * BM;
    const int n0 = blockIdx.x * BN;
    const int w = tid >> 6, l = tid & 63;
    const int wr = w >> 1, wcid = w & 1;
    const int lrow = l & 15, lk = (l >> 4) * 8;

    f32x4 acc[4][2] = {};

    for (int k0 = 0; k0 < K; k0 += BK) {
        __syncthreads();
        #pragma unroll
        for (int i = 0; i < 2; ++i) {
            int chunk = i * 256 + tid;
            int row = chunk >> 2;
            int colb = (chunk & 3) * 16;
            load16_to_lds((const char*)(A + (size_t)(m0 + row) * K + k0) + colb, ((char*)lA) + chunk * 16);
        }
        {
            int chunk = tid;
            int row = chunk >> 2;
            int colb = (chunk & 3) * 16;
            load16_to_lds((const char*)(Bm + (size_t)(n0 + row) * K + k0) + colb, ((char*)lB) + chunk * 16);
        }
        __syncthreads();

        bf16x8 af[4], bfr[2];
        #pragma unroll
        for (int m = 0; m < 4; ++m)
            af[m] = *(const bf16x8*)&lA[wr * 64 + m * 16 + lrow][lk];
        #pragma unroll
        for (int n = 0; n < 2; ++n)
            bfr[n] = *(const bf16x8*)&lB[wcid * 32 + n * 16 + lrow][lk];
        #pragma unroll
        for (int m = 0; m < 4; ++m)
            #pragma unroll
            for (int n = 0; n < 2; ++n)
                acc[m][n] = __builtin_amdgcn_mfma_f32_16x16x32_bf16(af[m], bfr[n], acc[m][n], 0, 0, 0);
    }

    const int r4 = (l >> 4) * 4;
    const int cc = l & 15;
    #pragma unroll
    for (int m = 0; m < 4; ++m) {
        #pragma unroll
        for (int n = 0; n < 2; ++n) {
            int col = n0 + wcid * 32 + n * 16 + cc;
            float bv = bias[col];
            #pragma unroll
            for (int j = 0; j < 4; ++j) {
                int row = m0 + wr * 64 + m * 16 + r4 + j;
                float v = acc[m][n][j] + bv;
                if (relu) v = fmaxf(v, 0.f);
                if (OUT_BF16) ((ushort*)Cout)[(size_t)row * N + col] = f2bf(v);
                else          ((float*)Cout)[(size_t)row * N + col] = v;
            }
        }
    }
}

// ---------- heads ----------
__global__ __launch_bounds__(256) void heads_kernel(
    const float* __restrict__ x2,
    const float* __restrict__ wc, const float* __restrict__ bc,
    const float* __restrict__ wb, const float* __restrict__ bb,
    float* __restrict__ out)
{
    int w = threadIdx.x >> 6, l = threadIdx.x & 63;
    int row = blockIdx.x * 4 + w;
    const float* xr = x2 + (size_t)row * 1024;
    float acc[10];
    #pragma unroll
    for (int o = 0; o < 10; ++o) acc[o] = 0.f;
    for (int i = 0; i < 16; ++i) {
        int k = i * 64 + l;
        float xv = xr[k];
        #pragma unroll
        for (int o = 0; o < 2; ++o) acc[o] += xv * wc[o * 1024 + k];
        #pragma unroll
        for (int o = 0; o < 8; ++o) acc[2 + o] += xv * wb[o * 1024 + k];
    }
    #pragma unroll
    for (int o = 0; o < 10; ++o) {
        float v = acc[o];
        #pragma unroll
        for (int s = 32; s > 0; s >>= 1) v += __shfl_xor(v, s, 64);
        acc[o] = v;
    }
    if (l == 0) {
        float* cls = out;
        float* bbx = out + 2048 * 2;
        cls[row * 2 + 0] = acc[0] + bc[0];
        cls[row * 2 + 1] = acc[1] + bc[1];
        #pragma unroll
        for (int o = 0; o < 8; ++o) bbx[row * 8 + o] = acc[2 + o] + bb[o];
    }
}

// ---------- decode + softmax ----------
__global__ __launch_bounds__(256) void decode_kernel(
    const float* __restrict__ props, float* __restrict__ out)
{
    int r = blockIdx.x * 256 + threadIdx.x;
    if (r >= 2048) return;
    const float* cls = out;
    const float* bbx = out + 4096;
    float* boxes  = out + 20480;
    float* scores = out + 36864;
    float px1 = props[r * 4 + 0], py1 = props[r * 4 + 1];
    float px2 = props[r * 4 + 2], py2 = props[r * 4 + 3];
    float pw = px2 - px1, ph = py2 - py1;
    float cx = px1 + 0.5f * pw, cy = py1 + 0.5f * ph;
    const float CLIP = 4.135166556742356f;
    #pragma unroll
    for (int k = 0; k < 2; ++k) {
        float dx = bbx[r * 8 + k * 4 + 0] * 0.1f;
        float dy = bbx[r * 8 + k * 4 + 1] * 0.1f;
        float dw = fminf(bbx[r * 8 + k * 4 + 2] * 0.2f, CLIP);
        float dh = fminf(bbx[r * 8 + k * 4 + 3] * 0.2f, CLIP);
        float pcx = dx * pw + cx, pcy = dy * ph + cy;
        float ppw = expf(dw) * pw, pph = expf(dh) * ph;
        float v0 = pcx - 0.5f * ppw, v1 = pcy - 0.5f * pph;
        float v2 = pcx + 0.5f * ppw, v3 = pcy + 0.5f * pph;
        boxes[r * 8 + k * 4 + 0] = fminf(fmaxf(v0, 0.f), 1024.f);
        boxes[r * 8 + k * 4 + 1] = fminf(fmaxf(v1, 0.f), 1024.f);
        boxes[r * 8 + k * 4 + 2] = fminf(fmaxf(v2, 0.f), 1024.f);
        boxes[r * 8 + k * 4 + 3] = fminf(fmaxf(v3, 0.f), 1024.f);
    }
    float s0 = cls[r * 2], s1 = cls[r * 2 + 1];
    float m = fmaxf(s0, s1);
    float e0 = expf(s0 - m), e1 = expf(s1 - m);
    float inv = 1.f / (e0 + e1);
    scores[r * 2 + 0] = e0 * inv;
    scores[r * 2 + 1] = e1 * inv;
}

// ---------- launch ----------
extern "C" void kernel_launch(void* const* d_in, const int* in_sizes, int n_in,
                              void* d_out, int out_size, void* d_ws, size_t ws_size,
                              hipStream_t stream) {
    const float* feat  = (const float*)d_in[0];
    const float* props = (const float*)d_in[1];
    const float* w1    = (const float*)d_in[2];
    const float* b1    = (const float*)d_in[3];
    const float* w2    = (const float*)d_in[4];
    const float* b2    = (const float*)d_in[5];
    const float* wc    = (const float*)d_in[6];
    const float* bc    = (const float*)d_in[7];
    const float* wb    = (const float*)d_in[8];
    const float* bb    = (const float*)d_in[9];
    float* out = (float*)d_out;

    char* ws = (char*)d_ws;
    ushort* pooled = (ushort*)(ws);                          // 51,380,224 B
    ushort* w1b    = (ushort*)(ws + 51380224);               // 25,690,112 B
    ushort* w2b    = (ushort*)(ws + 51380224 + 25690112);    //  2,097,152 B
    ushort* x1     = (ushort*)(ws + 79167488);               //  4,194,304 B
    float*  x2     = (float*) (ws + 83361792);               //  8,388,608 B
    float*  featT  = (float*) (ws + 83361792);               // aliases x2 (dead by gemm2)
    float*  part   = (float*) (ws + 91750400);               // split-K partials
    const size_t WS_NEED8 = 91750400 + 67108864;             // splitK=8: 67.1 MB
    const size_t WS_NEED4 = 91750400 + 33554432;             // splitK=4: 33.5 MB

    const int M = 2048, N = 1024;
    const int MN = M * N;

    f32_to_bf16_kernel<<<12845056 / 1024, 256, 0, stream>>>(w1, w1b, 12845056);
    f32_to_bf16_kernel<<<1048576 / 1024, 256, 0, stream>>>(w2, w2b, 1048576);
    transpose_feat_kernel<<<512, 256, 0, stream>>>(feat, featT);
    roi_align_kernel<<<2048, 512, 0, stream>>>(featT, props, pooled);

    if (ws_size >= WS_NEED8) {
        // gemm1: K=12544, split-K=8 (klen 1568), grid 8x16x8 = 1024 (~4 blk/CU)
        gemm_bt_split<<<dim3(N / 128, M / 128, 8), 256, 0, stream>>>(pooled, w1b, part, M, N, 12544, 1568);
        reduce_split_kernel<true ><<<MN / 1024, 256, 0, stream>>>(part, b1, x1, MN, N, 8, 1);
        // gemm2: K=1024, split-K=8 (klen 128), grid 1024
        gemm_bt_split<<<dim3(N / 128, M / 128, 8), 256, 0, stream>>>(x1, w2b, part, M, N, 1024, 128);
        reduce_split_kernel<false><<<MN / 1024, 256, 0, stream>>>(part, b2, x2, MN, N, 8, 1);
    } else if (ws_size >= WS_NEED4) {
        gemm_bt_split<<<dim3(N / 128, M / 128, 4), 256, 0, stream>>>(pooled, w1b, part, M, N, 12544, 3136);
        reduce_split_kernel<true ><<<MN / 1024, 256, 0, stream>>>(part, b1, x1, MN, N, 4, 1);
        gemm_bt_split<<<dim3(N / 128, M / 128, 4), 256, 0, stream>>>(x1, w2b, part, M, N, 1024, 256);
        reduce_split_kernel<false><<<MN / 1024, 256, 0, stream>>>(part, b2, x2, MN, N, 4, 1);
    } else {
        gemm_bt<true ><<<dim3(N / 64, M / 128), 256, 0, stream>>>(pooled, w1b, b1, x1, M, N, 12544, 1);
        gemm_bt<false><<<dim3(N / 64, M / 128), 256, 0, stream>>>(x1, w2b, b2, x2, M, N, 1024, 1);
    }

    heads_kernel<<<512, 256, 0, stream>>>(x2, wc, bc, wb, bb, out);
    decode_kernel<<<8, 256, 0, stream>>>(props, out);
}

// Round 16
// 186.198 us; speedup vs baseline: 1.1408x; 1.0553x over previous
//
#include <hip/hip_runtime.h>
#include <hip/hip_bf16.h>
#include <stdint.h>

// ---------- common ----------
typedef __attribute__((ext_vector_type(8))) short bf16x8;
typedef __attribute__((ext_vector_type(4))) float f32x4;

__device__ __forceinline__ ushort f2bf(float f) {
    union { float f; uint32_t u; } c; c.f = f;
    uint32_t u = c.u;
    uint32_t r = (u + 0x7FFFu + ((u >> 16) & 1u)) >> 16;
    return (ushort)r;
}

__device__ __forceinline__ void load16_to_lds(const void* gsrc, void* ldst) {
    __builtin_amdgcn_global_load_lds(
        (const __attribute__((address_space(1))) uint32_t*)gsrc,
        (__attribute__((address_space(3))) uint32_t*)ldst,
        16, 0, 0);
}

// ---------- f32 -> bf16 convert ----------
__global__ __launch_bounds__(256) void f32_to_bf16_kernel(
    const float* __restrict__ in, ushort* __restrict__ out, int n)
{
    int i = (blockIdx.x * 256 + threadIdx.x) * 4;
    if (i >= n) return;
    float4 v = *(const float4*)(in + i);
    ushort4 o;
    o.x = f2bf(v.x); o.y = f2bf(v.y); o.z = f2bf(v.z); o.w = f2bf(v.w);
    *(ushort4*)(out + i) = o;
}

// ---------- feature transpose: [2,256,32,32] -> [2,32,32,256] ----------
__global__ __launch_bounds__(256) void transpose_feat_kernel(
    const float* __restrict__ feat, float* __restrict__ featT)
{
    int bc = blockIdx.x;
    int b = bc >> 8;
    int c = bc & 255;
    const float* src = feat + (size_t)bc * 1024;
    float* dst = featT + (size_t)b * 262144 + c;
    #pragma unroll
    for (int i = 0; i < 4; ++i) {
        int p = i * 256 + threadIdx.x;
        dst[(size_t)p * 256] = src[p];
    }
}

// ---------- ROI align v5: SEPARABLE ----------
__global__ __launch_bounds__(512) void roi_align_kernel(
    const float* __restrict__ featT, const float* __restrict__ props,
    ushort* __restrict__ pooled)
{
    int roi = blockIdx.x;
    int b = roi >> 10;
    __shared__ int   si0[28];
    __shared__ int   si1[28];
    __shared__ float sl[28];
    __shared__ float sv[28];
    __shared__ float Aw[7][10];
    __shared__ float Bw[7][10];
    __shared__ __align__(16) ushort outbuf[12544];
    int tid = threadIdx.x;
    if (tid < 28) {
        int axis = (tid >= 14) ? 1 : 0;
        int pp = tid - axis * 14;
        float c0 = props[roi * 4 + (axis ? 0 : 1)] * (1.f / 32.f);
        float c1 = props[roi * 4 + (axis ? 2 : 3)] * (1.f / 32.f);
        float sz = fmaxf(c1 - c0, 1.f);
        float bsz = sz * (1.f / 7.f);
        float g = (float)(pp >> 1) + ((float)(pp & 1) + 0.5f) * 0.5f;
        float c = c0 + g * bsz;
        float valid = (c > -1.f && c < 32.f) ? 1.f : 0.f;
        float cc = fminf(fmaxf(c, 0.f), 31.f);
        float fl = floorf(cc);
        int i0 = (int)fl;
        si0[tid] = i0;
        si1[tid] = min(i0 + 1, 31);
        sl[tid] = cc - fl;
        sv[tid] = valid;
    }
    __syncthreads();

    const int r0 = si0[0];
    const int c0 = si0[14];

    if (tid < 140) {
        int axis = tid / 70;
        int e = tid - axis * 70;
        int oy = e / 10, yy = e - oy * 10;
        int base = axis * 14;
        int org = axis ? c0 : r0;
        float wsum = 0.f;
        #pragma unroll
        for (int s = 0; s < 2; ++s) {
            int p = base + oy * 2 + s;
            float w = 0.f;
            if (si0[p] - org == yy) w += 1.f - sl[p];
            if (si1[p] - org == yy) w += sl[p];
            wsum += sv[p] * w;
        }
        wsum *= 0.5f;
        if (axis == 0) Aw[oy][yy] = wsum;
        else           Bw[oy][yy] = wsum;
    }
    __syncthreads();

    const int grp = tid >> 8;
    const int ch = tid & 255;
    const float* fbase = featT + (size_t)b * 262144 + ch;

    int xoff[10];
    #pragma unroll
    for (int x = 0; x < 10; ++x) xoff[x] = min(c0 + x, 31) * 256;

    if (grp == 0) {
        float t[4][10];
        #pragma unroll
        for (int oy = 0; oy < 4; ++oy)
            #pragma unroll
            for (int x = 0; x < 10; ++x) t[oy][x] = 0.f;
        #pragma unroll
        for (int y = 0; y < 10; ++y) {
            const float* frow = fbase + (size_t)min(r0 + y, 31) * 8192;
            float a0 = Aw[0][y], a1 = Aw[1][y], a2 = Aw[2][y], a3 = Aw[3][y];
            #pragma unroll
            for (int x = 0; x < 10; ++x) {
                float fv = frow[xoff[x]];
                t[0][x] += a0 * fv;
                t[1][x] += a1 * fv;
                t[2][x] += a2 * fv;
                t[3][x] += a3 * fv;
            }
        }
        #pragma unroll
        for (int oy = 0; oy < 4; ++oy)
            #pragma unroll
            for (int ox = 0; ox < 7; ++ox) {
                float o = 0.f;
                #pragma unroll
                for (int x = 0; x < 10; ++x) o += Bw[ox][x] * t[oy][x];
                outbuf[ch * 49 + oy * 7 + ox] = f2bf(o);
            }
    } else {
        float t[3][10];
        #pragma unroll
        for (int oy = 0; oy < 3; ++oy)
            #pragma unroll
            for (int x = 0; x < 10; ++x) t[oy][x] = 0.f;
        #pragma unroll
        for (int y = 0; y < 10; ++y) {
            const float* frow = fbase + (size_t)min(r0 + y, 31) * 8192;
            float a4 = Aw[4][y], a5 = Aw[5][y], a6 = Aw[6][y];
            #pragma unroll
            for (int x = 0; x < 10; ++x) {
                float fv = frow[xoff[x]];
                t[0][x] += a4 * fv;
                t[1][x] += a5 * fv;
                t[2][x] += a6 * fv;
            }
        }
        #pragma unroll
        for (int oy = 0; oy < 3; ++oy)
            #pragma unroll
            for (int ox = 0; ox < 7; ++ox) {
                float o = 0.f;
                #pragma unroll
                for (int x = 0; x < 10; ++x) o += Bw[ox][x] * t[oy][x];
                outbuf[ch * 49 + (4 + oy) * 7 + ox] = f2bf(o);
            }
    }
    __syncthreads();

    const uint4* src = (const uint4*)outbuf;
    uint4* dst = (uint4*)(pooled + (size_t)roi * 12544);
    #pragma unroll
    for (int i = 0; i < 4; ++i) {
        int idx = i * 512 + tid;
        if (idx < 1568) dst[idx] = src[idx];
    }
}

// ---------- split-K GEMM, BK=64, double-buffered 2-phase (R12 sync structure) ----------
// part[kb][M][N] = A[M,Kchunk] @ B[N,Kchunk]^T.  BM=BN=128, BK=64, 4 waves.
// Halves barrier/drain count vs BK=32 (28 steps vs 49 at klen=1792).
// LDS 64KB total -> 2 blocks/CU.  XOR swizzle col16 ^= row&7 (inverse on
// global source, linear LDS dest per gload_lds rule; same XOR on read;
// row&7 == lrow&7 for all fragment rows since wave/m offsets are mult of 8).
__global__ __launch_bounds__(256) void gemm_bt_split64(
    const ushort* __restrict__ A, const ushort* __restrict__ Bm,
    float* __restrict__ part, int M, int N, int K, int klen)
{
    constexpr int BK = 64;
    __shared__ __align__(16) ushort lA[2][128][BK];
    __shared__ __align__(16) ushort lB[2][128][BK];
    const int tid = threadIdx.x;

    // bijective XCD-chunked swizzle (nwg % 8 == 0)
    const int nbx = gridDim.x, nby = gridDim.y;
    const int nwg = nbx * nby * gridDim.z;
    const int d = blockIdx.x + nbx * (blockIdx.y + nby * blockIdx.z);
    const int t = (d & 7) * (nwg >> 3) + (d >> 3);
    const int n_blk = t % nbx;
    const int m_blk = (t / nbx) % nby;
    const int k_blk = t / (nbx * nby);

    const int m0 = m_blk * 128;
    const int n0 = n_blk * 128;
    const int k_start = k_blk * klen;

    const int w = tid >> 6, l = tid & 63;
    const int wr = w >> 1, wcid = w & 1;
    const int lrow = l & 15, khi = l >> 4;

    // staging: 4 chunks of A + 4 of B per thread (1024 x 16B chunks per tile)
    int srow[4], scolu[4];      // source col offset in ushorts (pre-swizzled)
    #pragma unroll
    for (int i = 0; i < 4; ++i) {
        int chunk = i * 256 + tid;
        srow[i] = chunk >> 3;                               // 8 chunks (128B) per row
        scolu[i] = ((chunk & 7) ^ (srow[i] & 7)) * 8;       // inverse swizzle on source
    }

    const int nsteps = klen / BK;

    // prologue: stage step 0 into buf 0
    #pragma unroll
    for (int i = 0; i < 4; ++i) {
        load16_to_lds(A + (size_t)(m0 + srow[i]) * K + k_start + scolu[i], ((char*)lA[0]) + (i * 256 + tid) * 16);
        load16_to_lds(Bm + (size_t)(n0 + srow[i]) * K + k_start + scolu[i], ((char*)lB[0]) + (i * 256 + tid) * 16);
    }
    __syncthreads();

    f32x4 acc[4][4] = {};
    int cur = 0;

    for (int ts = 0; ts < nsteps; ++ts) {
        if (ts + 1 < nsteps) {
            int k0 = k_start + (ts + 1) * BK;
            int nxt = cur ^ 1;
            #pragma unroll
            for (int i = 0; i < 4; ++i) {
                load16_to_lds(A + (size_t)(m0 + srow[i]) * K + k0 + scolu[i], ((char*)lA[nxt]) + (i * 256 + tid) * 16);
                load16_to_lds(Bm + (size_t)(n0 + srow[i]) * K + k0 + scolu[i], ((char*)lB[nxt]) + (i * 256 + tid) * 16);
            }
        }

        #pragma unroll
        for (int kk = 0; kk < 2; ++kk) {
            const int c16u = ((kk * 4 + khi) ^ (lrow & 7)) * 8;   // ushort offset
            bf16x8 af[4], bfr[4];
            #pragma unroll
            for (int m = 0; m < 4; ++m)
                af[m] = *(const bf16x8*)&lA[cur][wr * 64 + m * 16 + lrow][c16u];
            #pragma unroll
            for (int n = 0; n < 4; ++n)
                bfr[n] = *(const bf16x8*)&lB[cur][wcid * 64 + n * 16 + lrow][c16u];
            #pragma unroll
            for (int m = 0; m < 4; ++m)
                #pragma unroll
                for (int n = 0; n < 4; ++n)
                    acc[m][n] = __builtin_amdgcn_mfma_f32_16x16x32_bf16(af[m], bfr[n], acc[m][n], 0, 0, 0);
        }

        __syncthreads();   // drains vmcnt(0): next buf ready; reads of cur done
        cur ^= 1;
    }

    const int r4 = (l >> 4) * 4;
    const int cc = l & 15;
    float* pb = part + (size_t)k_blk * M * N;
    #pragma unroll
    for (int m = 0; m < 4; ++m) {
        #pragma unroll
        for (int n = 0; n < 4; ++n) {
            int col = n0 + wcid * 64 + n * 16 + cc;
            #pragma unroll
            for (int j = 0; j < 4; ++j) {
                int row = m0 + wr * 64 + m * 16 + r4 + j;
                pb[(size_t)row * N + col] = acc[m][n][j];
            }
        }
    }
}

// ---------- split-K GEMM, BK=32, double-buffered 2-phase (R12-proven; gemm2) ----------
__global__ __launch_bounds__(256) void gemm_bt_split(
    const ushort* __restrict__ A, const ushort* __restrict__ Bm,
    float* __restrict__ part, int M, int N, int K, int klen)
{
    constexpr int BK = 32;
    __shared__ __align__(16) ushort lA[2][128][BK];
    __shared__ __align__(16) ushort lB[2][128][BK];
    const int tid = threadIdx.x;

    const int nbx = gridDim.x, nby = gridDim.y;
    const int nwg = nbx * nby * gridDim.z;
    const int d = blockIdx.x + nbx * (blockIdx.y + nby * blockIdx.z);
    const int t = (d & 7) * (nwg >> 3) + (d >> 3);
    const int n_blk = t % nbx;
    const int m_blk = (t / nbx) % nby;
    const int k_blk = t / (nbx * nby);

    const int m0 = m_blk * 128;
    const int n0 = n_blk * 128;
    const int k_start = k_blk * klen;

    const int w = tid >> 6, l = tid & 63;
    const int wr = w >> 1, wcid = w & 1;
    const int lrow = l & 15;
    const int lkb = (((l >> 4) ^ ((lrow >> 1) & 3)) * 16);

    const int sc0 = tid, sc1 = 256 + tid;
    const int srow0 = sc0 >> 2, srow1 = sc1 >> 2;
    const int scol0 = ((sc0 & 3) ^ ((srow0 >> 1) & 3)) * 16;
    const int scol1 = ((sc1 & 3) ^ ((srow1 >> 1) & 3)) * 16;

    const int nsteps = klen / BK;

    {
        int k0 = k_start;
        load16_to_lds((const char*)(A + (size_t)(m0 + srow0) * K + k0) + scol0, ((char*)lA[0]) + sc0 * 16);
        load16_to_lds((const char*)(A + (size_t)(m0 + srow1) * K + k0) + scol1, ((char*)lA[0]) + sc1 * 16);
        load16_to_lds((const char*)(Bm + (size_t)(n0 + srow0) * K + k0) + scol0, ((char*)lB[0]) + sc0 * 16);
        load16_to_lds((const char*)(Bm + (size_t)(n0 + srow1) * K + k0) + scol1, ((char*)lB[0]) + sc1 * 16);
    }
    __syncthreads();

    f32x4 acc[4][4] = {};
    int cur = 0;

    for (int ts = 0; ts < nsteps; ++ts) {
        if (ts + 1 < nsteps) {
            int k0 = k_start + (ts + 1) * BK;
            int nxt = cur ^ 1;
            load16_to_lds((const char*)(A + (size_t)(m0 + srow0) * K + k0) + scol0, ((char*)lA[nxt]) + sc0 * 16);
            load16_to_lds((const char*)(A + (size_t)(m0 + srow1) * K + k0) + scol1, ((char*)lA[nxt]) + sc1 * 16);
            load16_to_lds((const char*)(Bm + (size_t)(n0 + srow0) * K + k0) + scol0, ((char*)lB[nxt]) + sc0 * 16);
            load16_to_lds((const char*)(Bm + (size_t)(n0 + srow1) * K + k0) + scol1, ((char*)lB[nxt]) + sc1 * 16);
        }

        bf16x8 af[4], bfr[4];
        #pragma unroll
        for (int m = 0; m < 4; ++m)
            af[m] = *(const bf16x8*)(((const char*)lA[cur]) + (wr * 64 + m * 16 + lrow) * 64 + lkb);
        #pragma unroll
        for (int n = 0; n < 4; ++n)
            bfr[n] = *(const bf16x8*)(((const char*)lB[cur]) + (wcid * 64 + n * 16 + lrow) * 64 + lkb);
        #pragma unroll
        for (int m = 0; m < 4; ++m)
            #pragma unroll
            for (int n = 0; n < 4; ++n)
                acc[m][n] = __builtin_amdgcn_mfma_f32_16x16x32_bf16(af[m], bfr[n], acc[m][n], 0, 0, 0);

        __syncthreads();
        cur ^= 1;
    }

    const int r4 = (l >> 4) * 4;
    const int cc = l & 15;
    float* pb = part + (size_t)k_blk * M * N;
    #pragma unroll
    for (int m = 0; m < 4; ++m) {
        #pragma unroll
        for (int n = 0; n < 4; ++n) {
            int col = n0 + wcid * 64 + n * 16 + cc;
            #pragma unroll
            for (int j = 0; j < 4; ++j) {
                int row = m0 + wr * 64 + m * 16 + r4 + j;
                pb[(size_t)row * N + col] = acc[m][n][j];
            }
        }
    }
}

// ---------- reduce split-K partials + bias + relu + optional bf16 cast ----------
template<bool OUT_BF16>
__global__ __launch_bounds__(256) void reduce_split_kernel(
    const float* __restrict__ part, const float* __restrict__ bias,
    void* __restrict__ out, int MN, int N, int S, int relu)
{
    int i4 = (blockIdx.x * 256 + threadIdx.x) * 4;
    if (i4 >= MN) return;
    float4 a = *(const float4*)(part + i4);
    for (int s = 1; s < S; ++s) {
        float4 b = *(const float4*)(part + (size_t)s * MN + i4);
        a.x += b.x; a.y += b.y; a.z += b.z; a.w += b.w;
    }
    int bc = i4 & (N - 1);
    float4 bv = *(const float4*)(bias + bc);
    a.x += bv.x; a.y += bv.y; a.z += bv.z; a.w += bv.w;
    if (relu) {
        a.x = fmaxf(a.x, 0.f); a.y = fmaxf(a.y, 0.f);
        a.z = fmaxf(a.z, 0.f); a.w = fmaxf(a.w, 0.f);
    }
    if (OUT_BF16) {
        ushort4 o; o.x = f2bf(a.x); o.y = f2bf(a.y); o.z = f2bf(a.z); o.w = f2bf(a.w);
        *(ushort4*)((ushort*)out + i4) = o;
    } else {
        *(float4*)((float*)out + i4) = a;
    }
}

// ---------- fallback fused GEMM ----------
template<bool OUT_BF16>
__global__ __launch_bounds__(256) void gemm_bt(
    const ushort* __restrict__ A, const ushort* __restrict__ Bm,
    const float* __restrict__ bias, void* __restrict__ Cout,
    int M, int N, int K, int relu)
{
    constexpr int BM = 128, BN = 64, BK = 32;
    __shared__ __align__(16) ushort lA[BM][BK];
    __shared__ __align__(16) ushort lB[BN][BK];
    const int tid = threadIdx.x;
    const int m0 = blockIdx.y * BM;
    const int n0 = blockIdx.x * BN;
    const int w = tid >> 6, l = tid & 63;
    const int wr = w >> 1, wcid = w & 1;
    const int lrow = l & 15, lk = (l >> 4) * 8;

    f32x4 acc[4][2] = {};

    for (int k0 = 0; k0 < K; k0 += BK) {
        __syncthreads();
        #pragma unroll
        for (int i = 0; i < 2; ++i) {
            int chunk = i * 256 + tid;
            int row = chunk >> 2;
            int colb = (chunk & 3) * 16;
            load16_to_lds((const char*)(A + (size_t)(m0 + row) * K + k0) + colb, ((char*)lA) + chunk * 16);
        }
        {
            int chunk = tid;
            int row = chunk >> 2;
            int colb = (chunk & 3) * 16;
            load16_to_lds((const char*)(Bm + (size_t)(n0 + row) * K + k0) + colb, ((char*)lB) + chunk * 16);
        }
        __syncthreads();

        bf16x8 af[4], bfr[2];
        #pragma unroll
        for (int m = 0; m < 4; ++m)
            af[m] = *(const bf16x8*)&lA[wr * 64 + m * 16 + lrow][lk];
        #pragma unroll
        for (int n = 0; n < 2; ++n)
            bfr[n] = *(const bf16x8*)&lB[wcid * 32 + n * 16 + lrow][lk];
        #pragma unroll
        for (int m = 0; m < 4; ++m)
            #pragma unroll
            for (int n = 0; n < 2; ++n)
                acc[m][n] = __builtin_amdgcn_mfma_f32_16x16x32_bf16(af[m], bfr[n], acc[m][n], 0, 0, 0);
    }

    const int r4 = (l >> 4) * 4;
    const int cc = l & 15;
    #pragma unroll
    for (int m = 0; m < 4; ++m) {
        #pragma unroll
        for (int n = 0; n < 2; ++n) {
            int col = n0 + wcid * 32 + n * 16 + cc;
            float bv = bias[col];
            #pragma unroll
            for (int j = 0; j < 4; ++j) {
                int row = m0 + wr * 64 + m * 16 + r4 + j;
                float v = acc[m][n][j] + bv;
                if (relu) v = fmaxf(v, 0.f);
                if (OUT_BF16) ((ushort*)Cout)[(size_t)row * N + col] = f2bf(v);
                else          ((float*)Cout)[(size_t)row * N + col] = v;
            }
        }
    }
}

// ---------- heads ----------
__global__ __launch_bounds__(256) void heads_kernel(
    const float* __restrict__ x2,
    const float* __restrict__ wc, const float* __restrict__ bc,
    const float* __restrict__ wb, const float* __restrict__ bb,
    float* __restrict__ out)
{
    int w = threadIdx.x >> 6, l = threadIdx.x & 63;
    int row = blockIdx.x * 4 + w;
    const float* xr = x2 + (size_t)row * 1024;
    float acc[10];
    #pragma unroll
    for (int o = 0; o < 10; ++o) acc[o] = 0.f;
    for (int i = 0; i < 16; ++i) {
        int k = i * 64 + l;
        float xv = xr[k];
        #pragma unroll
        for (int o = 0; o < 2; ++o) acc[o] += xv * wc[o * 1024 + k];
        #pragma unroll
        for (int o = 0; o < 8; ++o) acc[2 + o] += xv * wb[o * 1024 + k];
    }
    #pragma unroll
    for (int o = 0; o < 10; ++o) {
        float v = acc[o];
        #pragma unroll
        for (int s = 32; s > 0; s >>= 1) v += __shfl_xor(v, s, 64);
        acc[o] = v;
    }
    if (l == 0) {
        float* cls = out;
        float* bbx = out + 2048 * 2;
        cls[row * 2 + 0] = acc[0] + bc[0];
        cls[row * 2 + 1] = acc[1] + bc[1];
        #pragma unroll
        for (int o = 0; o < 8; ++o) bbx[row * 8 + o] = acc[2 + o] + bb[o];
    }
}

// ---------- decode + softmax ----------
__global__ __launch_bounds__(256) void decode_kernel(
    const float* __restrict__ props, float* __restrict__ out)
{
    int r = blockIdx.x * 256 + threadIdx.x;
    if (r >= 2048) return;
    const float* cls = out;
    const float* bbx = out + 4096;
    float* boxes  = out + 20480;
    float* scores = out + 36864;
    float px1 = props[r * 4 + 0], py1 = props[r * 4 + 1];
    float px2 = props[r * 4 + 2], py2 = props[r * 4 + 3];
    float pw = px2 - px1, ph = py2 - py1;
    float cx = px1 + 0.5f * pw, cy = py1 + 0.5f * ph;
    const float CLIP = 4.135166556742356f;
    #pragma unroll
    for (int k = 0; k < 2; ++k) {
        float dx = bbx[r * 8 + k * 4 + 0] * 0.1f;
        float dy = bbx[r * 8 + k * 4 + 1] * 0.1f;
        float dw = fminf(bbx[r * 8 + k * 4 + 2] * 0.2f, CLIP);
        float dh = fminf(bbx[r * 8 + k * 4 + 3] * 0.2f, CLIP);
        float pcx = dx * pw + cx, pcy = dy * ph + cy;
        float ppw = expf(dw) * pw, pph = expf(dh) * ph;
        float v0 = pcx - 0.5f * ppw, v1 = pcy - 0.5f * pph;
        float v2 = pcx + 0.5f * ppw, v3 = pcy + 0.5f * pph;
        boxes[r * 8 + k * 4 + 0] = fminf(fmaxf(v0, 0.f), 1024.f);
        boxes[r * 8 + k * 4 + 1] = fminf(fmaxf(v1, 0.f), 1024.f);
        boxes[r * 8 + k * 4 + 2] = fminf(fmaxf(v2, 0.f), 1024.f);
        boxes[r * 8 + k * 4 + 3] = fminf(fmaxf(v3, 0.f), 1024.f);
    }
    float s0 = cls[r * 2], s1 = cls[r * 2 + 1];
    float m = fmaxf(s0, s1);
    float e0 = expf(s0 - m), e1 = expf(s1 - m);
    float inv = 1.f / (e0 + e1);
    scores[r * 2 + 0] = e0 * inv;
    scores[r * 2 + 1] = e1 * inv;
}

// ---------- launch ----------
extern "C" void kernel_launch(void* const* d_in, const int* in_sizes, int n_in,
                              void* d_out, int out_size, void* d_ws, size_t ws_size,
                              hipStream_t stream) {
    const float* feat  = (const float*)d_in[0];
    const float* props = (const float*)d_in[1];
    const float* w1    = (const float*)d_in[2];
    const float* b1    = (const float*)d_in[3];
    const float* w2    = (const float*)d_in[4];
    const float* b2    = (const float*)d_in[5];
    const float* wc    = (const float*)d_in[6];
    const float* bc    = (const float*)d_in[7];
    const float* wb    = (const float*)d_in[8];
    const float* bb    = (const float*)d_in[9];
    float* out = (float*)d_out;

    char* ws = (char*)d_ws;
    ushort* pooled = (ushort*)(ws);                          // 51,380,224 B
    ushort* w1b    = (ushort*)(ws + 51380224);               // 25,690,112 B
    ushort* w2b    = (ushort*)(ws + 51380224 + 25690112);    //  2,097,152 B
    ushort* x1     = (ushort*)(ws + 79167488);               //  4,194,304 B
    float*  x2     = (float*) (ws + 83361792);               //  8,388,608 B
    float*  featT  = (float*) (ws + 83361792);               // aliases x2 (dead by gemm2)
    float*  part   = (float*) (ws + 91750400);               // split-K partials
    const size_t WS_NEED7 = 91750400 + (size_t)7 * 8388608;  // splitK=7: 58.7 MB
    const size_t WS_NEED4 = 91750400 + 33554432;             // splitK=4: 33.5 MB

    const int M = 2048, N = 1024;
    const int MN = M * N;

    f32_to_bf16_kernel<<<12845056 / 1024, 256, 0, stream>>>(w1, w1b, 12845056);
    f32_to_bf16_kernel<<<1048576 / 1024, 256, 0, stream>>>(w2, w2b, 1048576);
    transpose_feat_kernel<<<512, 256, 0, stream>>>(feat, featT);
    roi_align_kernel<<<2048, 512, 0, stream>>>(featT, props, pooled);

    if (ws_size >= WS_NEED7) {
        // gemm1: K=12544, BK=64, split-K=7 (klen 1792 = 28 steps), grid 8x16x7 = 896
        gemm_bt_split64<<<dim3(N / 128, M / 128, 7), 256, 0, stream>>>(pooled, w1b, part, M, N, 12544, 1792);
        reduce_split_kernel<true ><<<MN / 1024, 256, 0, stream>>>(part, b1, x1, MN, N, 7, 1);
        // gemm2: K=1024, BK=32, split-K=4 (klen 256) — R12-proven config
        gemm_bt_split<<<dim3(N / 128, M / 128, 4), 256, 0, stream>>>(x1, w2b, part, M, N, 1024, 256);
        reduce_split_kernel<false><<<MN / 1024, 256, 0, stream>>>(part, b2, x2, MN, N, 4, 1);
    } else if (ws_size >= WS_NEED4) {
        gemm_bt_split<<<dim3(N / 128, M / 128, 4), 256, 0, stream>>>(pooled, w1b, part, M, N, 12544, 3136);
        reduce_split_kernel<true ><<<MN / 1024, 256, 0, stream>>>(part, b1, x1, MN, N, 4, 1);
        gemm_bt_split<<<dim3(N / 128, M / 128, 4), 256, 0, stream>>>(x1, w2b, part, M, N, 1024, 256);
        reduce_split_kernel<false><<<MN / 1024, 256, 0, stream>>>(part, b2, x2, MN, N, 4, 1);
    } else {
        gemm_bt<true ><<<dim3(N / 64, M / 128), 256, 0, stream>>>(pooled, w1b, b1, x1, M, N, 12544, 1);
        gemm_bt<false><<<dim3(N / 64, M / 128), 256, 0, stream>>>(x1, w2b, b2, x2, M, N, 1024, 1);
    }

    heads_kernel<<<512, 256, 0, stream>>>(x2, wc, bc, wb, bb, out);
    decode_kernel<<<8, 256, 0, stream>>>(props, out);
}